// Round 13
// baseline (518.479 us; speedup 1.0000x reference)
//
#include <hip/hip_runtime.h>
#include <hip/hip_bf16.h>

#define N_NODES 500000
#define E_EDGES 500000
#define FDIM 128
#define BN_EPS 1e-3f
#define OFFS 500001  // per-side stride of the offsets array

// ws layout (in floats):
//   [0, 16384)        buckets: 64 x (sum[128], sumsq[128]); after bn_finalize the
//                     first 512 floats are reused as gbias2 (folded GRU biases)
//   [16384, 16640)    scaleshift: scale[128], shift[128]
//   [16640, 65792)    pw  (gru weights)  bf16 fragment-order, 192 KB
//                     side 0 (a-side) is SCALED by BN scale post-bn_finalize
//   [65792, 82176)    pw2 (aggre weights) bf16 fragment-order, 64 KB
//   [82176, +32e6)    xbf  [N][128] bf16 (128 MB)
//   [.., +32e6)       a_bf [N][128] bf16 (128 MB)
#define WS_BUCKETS 0
#define WS_SCALESHIFT 16384
#define WS_PW 16640
#define WS_PW2 65792
#define WS_XBF 82176

// d_out u32 scratch layout (CSR only; dead before gru writes d_out):
#define SO_CNT 0
#define SO_OFF 1000000
#define SO_PART 2100000
#define SO_CUR 2200000
#define SO_SRC 3200000   // ends at 16.8 MB

typedef __attribute__((ext_vector_type(4))) float v4f;
typedef __attribute__((ext_vector_type(8))) __bf16 v8bf;

__device__ __forceinline__ unsigned f2bf_u(float f) {
  unsigned u = __float_as_uint(f);
  return ((u + 0x7FFF + ((u >> 16) & 1)) >> 16) & 0xFFFF;
}
__device__ __forceinline__ unsigned f2bf2(float a, float b) {
  return f2bf_u(a) | (f2bf_u(b) << 16);
}
__device__ __forceinline__ float bf2f(unsigned short u) {
  return __uint_as_float((unsigned)u << 16);
}
__device__ __forceinline__ float fast_sigmoid(float x) {
  float e = __expf(-x);
  return __builtin_amdgcn_rcpf(1.f + e);
}
// tanh(y) = 2*sigmoid(2y) - 1 ; saturates correctly at +/-inf without clamps.
__device__ __forceinline__ float fast_tanh(float x) {
  float e = __expf(-2.f * x);
  return 2.f * __builtin_amdgcn_rcpf(1.f + e) - 1.f;
}

__device__ __forceinline__ void acc16(float* a, uint4 u0, uint4 u1) {
  a[0] += bf2f((unsigned short)(u0.x & 0xffff)); a[1] += __uint_as_float(u0.x & 0xffff0000u);
  a[2] += bf2f((unsigned short)(u0.y & 0xffff)); a[3] += __uint_as_float(u0.y & 0xffff0000u);
  a[4] += bf2f((unsigned short)(u0.z & 0xffff)); a[5] += __uint_as_float(u0.z & 0xffff0000u);
  a[6] += bf2f((unsigned short)(u0.w & 0xffff)); a[7] += __uint_as_float(u0.w & 0xffff0000u);
  a[8] += bf2f((unsigned short)(u1.x & 0xffff)); a[9] += __uint_as_float(u1.x & 0xffff0000u);
  a[10] += bf2f((unsigned short)(u1.y & 0xffff)); a[11] += __uint_as_float(u1.y & 0xffff0000u);
  a[12] += bf2f((unsigned short)(u1.z & 0xffff)); a[13] += __uint_as_float(u1.z & 0xffff0000u);
  a[14] += bf2f((unsigned short)(u1.w & 0xffff)); a[15] += __uint_as_float(u1.w & 0xffff0000u);
}

// ---------------------------------------------------------------- weight repack
__global__ __launch_bounds__(256) void repack_gru_scaled(
    const float* __restrict__ gk, const float* __restrict__ rk,
    const float* __restrict__ scaleshift, unsigned short* __restrict__ pw) {
  int idx = blockIdx.x * 256 + threadIdx.x;  // 0..98303
  int side = idx / 49152;
  int rem = idx % 49152;
  int gate = rem >> 14;
  int rr = rem & 16383;
  int c = rr >> 7, k = rr & 127;
  const float* src = side ? rk : gk;
  float v = src[k * 384 + gate * 128 + c];
  if (side == 0) v *= scaleshift[k];
  int w = c >> 5, nb = (c >> 4) & 1, l15 = c & 15;
  int ks = k >> 5, lg = (k >> 3) & 3, j = k & 7;
  int lane = lg * 16 + l15;
  int e = w * 24576 + ks * 6144 + nb * 3072 + gate * 1024 + side * 512 + lane * 8 + j;
  pw[e] = (unsigned short)f2bf_u(v);
}

// Folded GRU bias (incl. shift @ gk): see round-12 comment.
__global__ __launch_bounds__(512) void bias_fold(
    const float* __restrict__ gk, const float* __restrict__ gbias,
    const float* __restrict__ scaleshift, float* __restrict__ gbias2) {
  __shared__ float sh[128];
  int j = threadIdx.x;
  if (j < 128) sh[j] = scaleshift[128 + j];
  __syncthreads();
  if (j < 384) {
    float s = 0.f;
#pragma unroll 8
    for (int k = 0; k < 128; ++k) s += sh[k] * gk[k * 384 + j];
    float o = gbias[j] + s;
    if (j < 256) o += gbias[384 + j];
    gbias2[j] = o;
  } else {
    gbias2[j] = gbias[256 + j];  // 640 + (j-384)
  }
}

__global__ __launch_bounds__(256) void repack_w(
    const float* __restrict__ w_next, const float* __restrict__ w_prev,
    unsigned short* __restrict__ pw2) {
  int idx = blockIdx.x * 256 + threadIdx.x;  // 0..32767
  int side = idx >> 14;
  int rr = idx & 16383;
  int c = rr >> 7, k = rr & 127;
  const float* src = side ? w_prev : w_next;
  float v = src[k * 128 + c];
  int nh = c >> 6, nb = (c >> 4) & 3, l15 = c & 15;
  int ks = k >> 5, lg = (k >> 3) & 3, j = k & 7;
  int lane = lg * 16 + l15;
  int e = nh * 16384 + ks * 4096 + nb * 1024 + side * 512 + lane * 8 + j;
  pw2[e] = (unsigned short)f2bf_u(v);
}

// ---------------------------------------------------------------- x -> bf16 (+fused edge histogram)
__global__ __launch_bounds__(256) void xbf_hist_kernel(
    const float* __restrict__ x, unsigned short* __restrict__ xbf,
    const int* __restrict__ pp, const int* __restrict__ pn,
    unsigned* __restrict__ cnt) {
  size_t i = ((size_t)blockIdx.x * 256 + threadIdx.x) * 8;
  if (i < (size_t)N_NODES * FDIM) {
    float4 a = *(const float4*)(x + i);
    float4 b = *(const float4*)(x + i + 4);
    uint4 o = make_uint4(f2bf2(a.x, a.y), f2bf2(a.z, a.w), f2bf2(b.x, b.y),
                         f2bf2(b.z, b.w));
    *(uint4*)(xbf + i) = o;
  }
  int e = blockIdx.x * 256 + threadIdx.x;
  if (e < 2 * E_EDGES) {
    int side = e >= E_EDGES;
    const int* pair = side ? pn + 2 * (e - E_EDGES) : pp + 2 * e;
    atomicAdd(&cnt[side * N_NODES + pair[0]], 1u);
  }
}

// ---------------------------------------------------------------- CSR build
__global__ __launch_bounds__(256) void scan1_kernel(const unsigned* __restrict__ cnt,
                                                    unsigned* __restrict__ off,
                                                    unsigned* __restrict__ part) {
  __shared__ unsigned ls[256];
  int side = blockIdx.y;
  int b = blockIdx.x;
  int td = threadIdx.x;
  int base = b * 1024 + td * 4;
  const unsigned* c = cnt + (size_t)side * N_NODES;
  unsigned v0 = 0, v1 = 0, v2 = 0, v3 = 0;
  if (base + 3 < N_NODES) {
    v0 = c[base]; v1 = c[base + 1]; v2 = c[base + 2]; v3 = c[base + 3];
  } else {
    if (base < N_NODES) v0 = c[base];
    if (base + 1 < N_NODES) v1 = c[base + 1];
    if (base + 2 < N_NODES) v2 = c[base + 2];
  }
  unsigned s = v0 + v1 + v2 + v3;
  ls[td] = s;
  __syncthreads();
  unsigned run = s;
  for (int st = 1; st < 256; st <<= 1) {
    unsigned o = (td >= st) ? ls[td - st] : 0u;
    __syncthreads();
    run += o;
    ls[td] = run;
    __syncthreads();
  }
  unsigned excl = run - s;
  unsigned* oo = off + (size_t)side * OFFS;
  if (base < N_NODES) oo[base] = excl;
  if (base + 1 < N_NODES) oo[base + 1] = excl + v0;
  if (base + 2 < N_NODES) oo[base + 2] = excl + v0 + v1;
  if (base + 3 < N_NODES) oo[base + 3] = excl + v0 + v1 + v2;
  if (td == 255) part[side * 512 + b] = run;
}

__global__ __launch_bounds__(1024) void scan2_kernel(unsigned* __restrict__ part) {
  __shared__ unsigned ls[1024];
  int td = threadIdx.x;
  int b = td & 511;
  unsigned s = part[td];
  ls[td] = s;
  __syncthreads();
  unsigned run = s;
  for (int st = 1; st < 512; st <<= 1) {
    unsigned o = (b >= st) ? ls[td - st] : 0u;
    __syncthreads();
    run += o;
    ls[td] = run;
    __syncthreads();
  }
  part[td] = run - s;
}

__global__ __launch_bounds__(256) void scan3_kernel(unsigned* __restrict__ off,
                                                    const unsigned* __restrict__ part,
                                                    unsigned* __restrict__ cur) {
  int side = blockIdx.y;
  int i = blockIdx.x * 256 + threadIdx.x;
  if (i < N_NODES) {
    unsigned v = off[(size_t)side * OFFS + i] + part[side * 512 + (i >> 10)];
    off[(size_t)side * OFFS + i] = v;
    cur[(size_t)side * N_NODES + i] = v;
  }
  if (i == 0) off[(size_t)side * OFFS + N_NODES] = E_EDGES;
}

__global__ __launch_bounds__(256) void reorder_kernel(const int* __restrict__ pp,
                                                      const int* __restrict__ pn,
                                                      unsigned* __restrict__ cur,
                                                      unsigned* __restrict__ srcbuf) {
  int i = blockIdx.x * 256 + threadIdx.x;
  if (i >= 2 * E_EDGES) return;
  int side = i >= E_EDGES;
  const int* pair = side ? pn + 2 * (i - E_EDGES) : pp + 2 * i;
  unsigned pos = atomicAdd(&cur[(size_t)side * N_NODES + pair[0]], 1u);
  srcbuf[(size_t)side * E_EDGES + pos] = (unsigned)pair[1];
}

// ---------------------------------------------------------------- fused gather + aggre MFMA + relu + BN-stats
// Gather: BOTH sides' CSR edge chains interleaved in one loop -> 2 independent
// dependent-load chains in flight per thread (halves serial latency).
// Per-side accumulation order unchanged (numerics identical).
__global__ __launch_bounds__(256) void aggre_fused(
    const unsigned short* __restrict__ xbf, const unsigned* __restrict__ off,
    const unsigned* __restrict__ srcbuf, const unsigned short* __restrict__ pw2,
    const float* __restrict__ b, unsigned short* __restrict__ a_out,
    float* __restrict__ buckets) {
  __shared__ unsigned short Ap[32 * 128];   // 8 KB
  __shared__ unsigned short An[32 * 128];   // 8 KB
  __shared__ unsigned soff[2][33];
  __shared__ float rs[2][128];
  __shared__ float rq[2][128];
  int t = threadIdx.x;
  int r0 = blockIdx.x * 32;
  int rr = t >> 3, fc = t & 7;  // gather role: my row, my 16-feature chunk

  if (t < 33) soff[0][t] = off[r0 + t];
  if (t >= 64 && t < 97) soff[1][t - 64] = off[(size_t)OFFS + r0 + (t - 64)];
  __syncthreads();

  unsigned s0p = soff[0][rr], np = soff[0][rr + 1] - s0p;
  unsigned s0n = soff[1][rr], nn = soff[1][rr + 1] - s0n;
  const unsigned* slp = srcbuf;
  const unsigned* sln = srcbuf + E_EDGES;
  float ap[16], an[16];
#pragma unroll
  for (int i = 0; i < 16; ++i) { ap[i] = 0.f; an[i] = 0.f; }

  unsigned nmax = np > nn ? np : nn;
  for (unsigned j = 0; j < nmax; ++j) {
    bool hp = j < np, hn = j < nn;
    uint4 p0, p1, n0, n1;
    if (hp) {
      const unsigned short* p = xbf + (size_t)slp[s0p + j] * FDIM + fc * 16;
      p0 = *(const uint4*)p;
      p1 = *(const uint4*)(p + 8);
    }
    if (hn) {
      const unsigned short* p = xbf + (size_t)sln[s0n + j] * FDIM + fc * 16;
      n0 = *(const uint4*)p;
      n1 = *(const uint4*)(p + 8);
    }
    if (hp) acc16(ap, p0, p1);
    if (hn) acc16(an, n0, n1);
  }

  {
    int b0 = (rr * 256 + fc * 32) ^ ((rr & 7) << 4);
    int b1 = (rr * 256 + fc * 32 + 16) ^ ((rr & 7) << 4);
    uint4 o0 = make_uint4(f2bf2(ap[0], ap[1]), f2bf2(ap[2], ap[3]),
                          f2bf2(ap[4], ap[5]), f2bf2(ap[6], ap[7]));
    uint4 o1 = make_uint4(f2bf2(ap[8], ap[9]), f2bf2(ap[10], ap[11]),
                          f2bf2(ap[12], ap[13]), f2bf2(ap[14], ap[15]));
    *(uint4*)((char*)Ap + b0) = o0;
    *(uint4*)((char*)Ap + b1) = o1;
    uint4 e0 = make_uint4(f2bf2(an[0], an[1]), f2bf2(an[2], an[3]),
                          f2bf2(an[4], an[5]), f2bf2(an[6], an[7]));
    uint4 e1 = make_uint4(f2bf2(an[8], an[9]), f2bf2(an[10], an[11]),
                          f2bf2(an[12], an[13]), f2bf2(an[14], an[15]));
    *(uint4*)((char*)An + b0) = e0;
    *(uint4*)((char*)An + b1) = e1;
  }
  __syncthreads();

  // ---- MFMA phase ----
  int w = t >> 6, lane = t & 63;
  int m0 = (w & 1) * 16, nh = w >> 1;
  int l15 = lane & 15, lg = lane >> 4;

  v4f acc[4];
#pragma unroll
  for (int nb = 0; nb < 4; ++nb) acc[nb] = (v4f){0.f, 0.f, 0.f, 0.f};

#pragma unroll
  for (int ks = 0; ks < 4; ++ks) {
    int mm = m0 + l15;
    int byte = (mm * 256 + ks * 64 + lg * 16) ^ ((mm & 7) << 4);
    v8bf apf = __builtin_bit_cast(v8bf, *(const uint4*)((const char*)Ap + byte));
    v8bf anf = __builtin_bit_cast(v8bf, *(const uint4*)((const char*)An + byte));
    const unsigned short* wb = pw2 + nh * 16384 + ks * 4096 + lane * 8;
#pragma unroll
    for (int nb = 0; nb < 4; ++nb) {
      v8bf bn_ = __builtin_bit_cast(v8bf, *(const uint4*)(wb + nb * 1024));
      v8bf bp_ = __builtin_bit_cast(v8bf, *(const uint4*)(wb + nb * 1024 + 512));
      acc[nb] = __builtin_amdgcn_mfma_f32_16x16x32_bf16(anf, bn_, acc[nb], 0, 0, 0);
      acc[nb] = __builtin_amdgcn_mfma_f32_16x16x32_bf16(apf, bp_, acc[nb], 0, 0, 0);
    }
  }

  float s1[4], s2[4];
#pragma unroll
  for (int nb = 0; nb < 4; ++nb) {
    int c = nh * 64 + nb * 16 + l15;
    float bb = b[c];
    s1[nb] = 0.f;
    s2[nb] = 0.f;
#pragma unroll
    for (int r = 0; r < 4; ++r) {
      int row = r0 + m0 + 4 * lg + r;
      size_t o = (size_t)row * FDIM + c;
      float v = acc[nb][r] + bb + bf2f(xbf[o]);
      v = fmaxf(v, 0.f);
      a_out[o] = (unsigned short)f2bf_u(v);
      s1[nb] += v;
      s2[nb] += v * v;
    }
    s1[nb] += __shfl_xor(s1[nb], 16);
    s1[nb] += __shfl_xor(s1[nb], 32);
    s2[nb] += __shfl_xor(s2[nb], 16);
    s2[nb] += __shfl_xor(s2[nb], 32);
  }
  if (lane < 16) {
#pragma unroll
    for (int nb = 0; nb < 4; ++nb) {
      rs[w & 1][nh * 64 + nb * 16 + lane] = s1[nb];
      rq[w & 1][nh * 64 + nb * 16 + lane] = s2[nb];
    }
  }
  __syncthreads();
  if (t < 128) {
    float s = rs[0][t] + rs[1][t];
    float q = rq[0][t] + rq[1][t];
    float* bkt = buckets + (size_t)(blockIdx.x & 63) * 256;
    atomicAdd(bkt + t, s);
    atomicAdd(bkt + 128 + t, q);
  }
}

// ---------------------------------------------------------------- BN finalize
__global__ void bn_finalize(const float* __restrict__ buckets,
                            const float* __restrict__ gamma,
                            const float* __restrict__ beta,
                            float* __restrict__ scaleshift) {
  int t = threadIdx.x;  // 128
  float s = 0.f, q = 0.f;
  for (int j = 0; j < 64; ++j) {
    s += buckets[j * 256 + t];
    q += buckets[j * 256 + 128 + t];
  }
  float mean = s / (float)N_NODES;
  float var = q / (float)N_NODES - mean * mean;
  var = fmaxf(var, 0.f);
  float sc = gamma[t] * rsqrtf(var + BN_EPS);
  scaleshift[t] = sc;
  scaleshift[128 + t] = beta[t] - mean * sc;
}

// ---------------------------------------------------------------- GRU v7 (MFMA)
// 32 rows/block, 4 waves. BN folded into weights/biases -> raw uint4 staging.
// z/r side-fused accumulators; h from Ax LDS; cheap gates; NT out stores.
__global__ __launch_bounds__(256) void gru_mfma(
    const unsigned short* __restrict__ a_bf, const unsigned short* __restrict__ xbf,
    const unsigned short* __restrict__ pw, const float* __restrict__ gbias2,
    float* __restrict__ out) {
  __shared__ unsigned short Aa[32 * 128];  // raw a bf16, swizzled
  __shared__ unsigned short Ax[32 * 128];  // x bf16, swizzled
  int t = threadIdx.x;
  int r0 = blockIdx.x * 32;

#pragma unroll
  for (int i = 0; i < 2; ++i) {
    int q = t + 256 * i;  // 0..511 : 32 rows x 16 chunks of 8 feats
    int row = q >> 4, kq = q & 15;
    size_t g = (size_t)(r0 + row) * FDIM + kq * 8;
    uint4 av = *(const uint4*)(a_bf + g);
    uint4 xv = *(const uint4*)(xbf + g);
    int byte = (row * 256 + kq * 16) ^ ((row & 7) << 4);
    *(uint4*)((char*)Aa + byte) = av;  // raw copies — zero conversion VALU
    *(uint4*)((char*)Ax + byte) = xv;
  }
  __syncthreads();

  int w = t >> 6, lane = t & 63;
  int l15 = lane & 15, lg = lane >> 4;

  v4f az[2][2], ar[2][2], ah0[2][2], ah1[2][2];  // [m][nb]
#pragma unroll
  for (int m = 0; m < 2; ++m)
#pragma unroll
    for (int nb = 0; nb < 2; ++nb) {
      az[m][nb] = (v4f){0.f, 0.f, 0.f, 0.f};
      ar[m][nb] = (v4f){0.f, 0.f, 0.f, 0.f};
      ah0[m][nb] = (v4f){0.f, 0.f, 0.f, 0.f};
      ah1[m][nb] = (v4f){0.f, 0.f, 0.f, 0.f};
    }

#pragma unroll
  for (int ks = 0; ks < 4; ++ks) {
    v8bf aa[2], ax[2];
#pragma unroll
    for (int m = 0; m < 2; ++m) {
      int mm = m * 16 + l15;
      int byte = (mm * 256 + ks * 64 + lg * 16) ^ ((mm & 7) << 4);
      aa[m] = __builtin_bit_cast(v8bf, *(const uint4*)((const char*)Aa + byte));
      ax[m] = __builtin_bit_cast(v8bf, *(const uint4*)((const char*)Ax + byte));
    }
    const unsigned short* wb = pw + w * 24576 + ks * 6144 + lane * 8;
#pragma unroll
    for (int nb = 0; nb < 2; ++nb) {
      const unsigned short* wn = wb + nb * 3072;
      v8bf b0z = __builtin_bit_cast(v8bf, *(const uint4*)(wn));
      v8bf b1z = __builtin_bit_cast(v8bf, *(const uint4*)(wn + 512));
      v8bf b0r = __builtin_bit_cast(v8bf, *(const uint4*)(wn + 1024));
      v8bf b1r = __builtin_bit_cast(v8bf, *(const uint4*)(wn + 1536));
      v8bf b0h = __builtin_bit_cast(v8bf, *(const uint4*)(wn + 2048));
      v8bf b1h = __builtin_bit_cast(v8bf, *(const uint4*)(wn + 2560));
#pragma unroll
      for (int m = 0; m < 2; ++m) {
        az[m][nb] = __builtin_amdgcn_mfma_f32_16x16x32_bf16(aa[m], b0z, az[m][nb], 0, 0, 0);
        az[m][nb] = __builtin_amdgcn_mfma_f32_16x16x32_bf16(ax[m], b1z, az[m][nb], 0, 0, 0);
        ar[m][nb] = __builtin_amdgcn_mfma_f32_16x16x32_bf16(aa[m], b0r, ar[m][nb], 0, 0, 0);
        ar[m][nb] = __builtin_amdgcn_mfma_f32_16x16x32_bf16(ax[m], b1r, ar[m][nb], 0, 0, 0);
        ah0[m][nb] = __builtin_amdgcn_mfma_f32_16x16x32_bf16(aa[m], b0h, ah0[m][nb], 0, 0, 0);
        ah1[m][nb] = __builtin_amdgcn_mfma_f32_16x16x32_bf16(ax[m], b1h, ah1[m][nb], 0, 0, 0);
      }
    }
  }

#pragma unroll
  for (int nb = 0; nb < 2; ++nb) {
    int c = w * 32 + nb * 16 + l15;
    float bz = gbias2[c];
    float br = gbias2[128 + c];
    float bh0 = gbias2[256 + c];
    float bh1 = gbias2[384 + c];
#pragma unroll
    for (int m = 0; m < 2; ++m) {
#pragma unroll
      for (int r = 0; r < 4; ++r) {
        int rl = m * 16 + 4 * lg + r;
        int row = r0 + rl;
        float z = fast_sigmoid(az[m][nb][r] + bz);
        float rg = fast_sigmoid(ar[m][nb][r] + br);
        float hc = fast_tanh(ah0[m][nb][r] + bh0 + rg * (ah1[m][nb][r] + bh1));
        int hb = (rl * 256 + c * 2) ^ ((rl & 7) << 4);
        float h = bf2f(*(const unsigned short*)((const char*)Ax + hb));
        __builtin_nontemporal_store(hc + z * (h - hc),
                                    out + (size_t)row * FDIM + c);
      }
    }
  }
}

// ---------------------------------------------------------------- launch
extern "C" void kernel_launch(void* const* d_in, const int* in_sizes, int n_in,
                              void* d_out, int out_size, void* d_ws, size_t ws_size,
                              hipStream_t stream) {
  const float* x = (const float*)d_in[0];
  const int* pp = (const int*)d_in[1];
  const int* pn = (const int*)d_in[2];
  const float* w_next = (const float*)d_in[3];
  const float* w_prev = (const float*)d_in[4];
  const float* b = (const float*)d_in[5];
  const float* gamma = (const float*)d_in[6];
  const float* beta = (const float*)d_in[7];
  const float* gk = (const float*)d_in[8];
  const float* rk = (const float*)d_in[9];
  const float* gbias = (const float*)d_in[10];
  float* out = (float*)d_out;
  float* ws = (float*)d_ws;

  float* buckets = ws + WS_BUCKETS;
  float* gbias2 = ws + WS_BUCKETS;  // reuses buckets after bn_finalize
  float* scaleshift = ws + WS_SCALESHIFT;
  unsigned short* pw = (unsigned short*)(ws + WS_PW);
  unsigned short* pw2 = (unsigned short*)(ws + WS_PW2);
  unsigned short* xbf = (unsigned short*)(ws + WS_XBF);
  unsigned short* a_bf = xbf + (size_t)N_NODES * FDIM;  // 128 MB after xbf

  unsigned* u = (unsigned*)d_out;  // CSR scratch; dead before gru writes out
  unsigned* cnt = u + SO_CNT;
  unsigned* off = u + SO_OFF;
  unsigned* part = u + SO_PART;
  unsigned* cur = u + SO_CUR;
  unsigned* srcbuf = u + SO_SRC;

  hipMemsetAsync(cnt, 0, 2u * N_NODES * sizeof(unsigned), stream);
  hipMemsetAsync(part, 0, 1024 * sizeof(unsigned), stream);
  hipMemsetAsync(buckets, 0, (16384 + 256) * sizeof(float), stream);

  repack_w<<<128, 256, 0, stream>>>(w_next, w_prev, pw2);
  xbf_hist_kernel<<<31250, 256, 0, stream>>>(x, xbf, pp, pn, cnt);

  scan1_kernel<<<dim3(489, 2), 256, 0, stream>>>(cnt, off, part);
  scan2_kernel<<<1, 1024, 0, stream>>>(part);
  scan3_kernel<<<dim3((N_NODES + 255) / 256, 2), 256, 0, stream>>>(off, part, cur);
  reorder_kernel<<<(2 * E_EDGES + 255) / 256, 256, 0, stream>>>(pp, pn, cur, srcbuf);

  aggre_fused<<<N_NODES / 32, 256, 0, stream>>>(xbf, off, srcbuf, pw2, b, a_bf,
                                                buckets);
  bn_finalize<<<1, 128, 0, stream>>>(buckets, gamma, beta, scaleshift);
  // post-BN: fold scale into a-side GRU weights, shift@W into biases
  repack_gru_scaled<<<384, 256, 0, stream>>>(gk, rk, scaleshift, pw);
  bias_fold<<<1, 512, 0, stream>>>(gk, gbias, scaleshift, gbias2);
  gru_mfma<<<N_NODES / 32, 256, 0, stream>>>(a_bf, xbf, pw, gbias2, out);
}

// Round 14
// 509.886 us; speedup vs baseline: 1.0169x; 1.0169x over previous
//
#include <hip/hip_runtime.h>
#include <hip/hip_bf16.h>

#define N_NODES 500000
#define E_EDGES 500000
#define FDIM 128
#define BN_EPS 1e-3f
#define OFFS 500001  // per-side stride of the offsets array
#define SCAP 160     // staged src indices per side per block (fallback if exceeded)

// ws layout (in floats):
//   [0, 16384)        buckets: 64 x (sum[128], sumsq[128]); after bn_finalize the
//                     first 512 floats are reused as gbias2 (folded GRU biases)
//   [16384, 16640)    scaleshift: scale[128], shift[128]
//   [16640, 65792)    pw  (gru weights)  bf16 fragment-order, 192 KB
//                     side 0 (a-side) is SCALED by BN scale post-bn_finalize
//   [65792, 82176)    pw2 (aggre weights) bf16 fragment-order, 64 KB
//   [82176, +32e6)    xbf  [N][128] bf16 (128 MB)
//   [.., +32e6)       a_bf [N][128] bf16 (128 MB)
#define WS_BUCKETS 0
#define WS_SCALESHIFT 16384
#define WS_PW 16640
#define WS_PW2 65792
#define WS_XBF 82176

// d_out u32 scratch layout (CSR only; dead before gru writes d_out):
#define SO_CNT 0
#define SO_OFF 1000000
#define SO_PART 2100000
#define SO_CUR 2200000
#define SO_SRC 3200000   // ends at 16.8 MB

typedef __attribute__((ext_vector_type(4))) float v4f;
typedef __attribute__((ext_vector_type(8))) __bf16 v8bf;

__device__ __forceinline__ unsigned f2bf_u(float f) {
  unsigned u = __float_as_uint(f);
  return ((u + 0x7FFF + ((u >> 16) & 1)) >> 16) & 0xFFFF;
}
__device__ __forceinline__ unsigned f2bf2(float a, float b) {
  return f2bf_u(a) | (f2bf_u(b) << 16);
}
__device__ __forceinline__ float bf2f(unsigned short u) {
  return __uint_as_float((unsigned)u << 16);
}
__device__ __forceinline__ float fast_sigmoid(float x) {
  float e = __expf(-x);
  return __builtin_amdgcn_rcpf(1.f + e);
}
// tanh(y) = 2*sigmoid(2y) - 1 ; saturates correctly at +/-inf without clamps.
__device__ __forceinline__ float fast_tanh(float x) {
  float e = __expf(-2.f * x);
  return 2.f * __builtin_amdgcn_rcpf(1.f + e) - 1.f;
}

__device__ __forceinline__ void acc16(float* a, uint4 u0, uint4 u1) {
  a[0] += bf2f((unsigned short)(u0.x & 0xffff)); a[1] += __uint_as_float(u0.x & 0xffff0000u);
  a[2] += bf2f((unsigned short)(u0.y & 0xffff)); a[3] += __uint_as_float(u0.y & 0xffff0000u);
  a[4] += bf2f((unsigned short)(u0.z & 0xffff)); a[5] += __uint_as_float(u0.z & 0xffff0000u);
  a[6] += bf2f((unsigned short)(u0.w & 0xffff)); a[7] += __uint_as_float(u0.w & 0xffff0000u);
  a[8] += bf2f((unsigned short)(u1.x & 0xffff)); a[9] += __uint_as_float(u1.x & 0xffff0000u);
  a[10] += bf2f((unsigned short)(u1.y & 0xffff)); a[11] += __uint_as_float(u1.y & 0xffff0000u);
  a[12] += bf2f((unsigned short)(u1.z & 0xffff)); a[13] += __uint_as_float(u1.z & 0xffff0000u);
  a[14] += bf2f((unsigned short)(u1.w & 0xffff)); a[15] += __uint_as_float(u1.w & 0xffff0000u);
}

// ---------------------------------------------------------------- weight repack
__global__ __launch_bounds__(256) void repack_gru_scaled(
    const float* __restrict__ gk, const float* __restrict__ rk,
    const float* __restrict__ scaleshift, unsigned short* __restrict__ pw) {
  int idx = blockIdx.x * 256 + threadIdx.x;  // 0..98303
  int side = idx / 49152;
  int rem = idx % 49152;
  int gate = rem >> 14;
  int rr = rem & 16383;
  int c = rr >> 7, k = rr & 127;
  const float* src = side ? rk : gk;
  float v = src[k * 384 + gate * 128 + c];
  if (side == 0) v *= scaleshift[k];
  int w = c >> 5, nb = (c >> 4) & 1, l15 = c & 15;
  int ks = k >> 5, lg = (k >> 3) & 3, j = k & 7;
  int lane = lg * 16 + l15;
  int e = w * 24576 + ks * 6144 + nb * 3072 + gate * 1024 + side * 512 + lane * 8 + j;
  pw[e] = (unsigned short)f2bf_u(v);
}

// Folded GRU bias (incl. shift @ gk).
__global__ __launch_bounds__(512) void bias_fold(
    const float* __restrict__ gk, const float* __restrict__ gbias,
    const float* __restrict__ scaleshift, float* __restrict__ gbias2) {
  __shared__ float sh[128];
  int j = threadIdx.x;
  if (j < 128) sh[j] = scaleshift[128 + j];
  __syncthreads();
  if (j < 384) {
    float s = 0.f;
#pragma unroll 8
    for (int k = 0; k < 128; ++k) s += sh[k] * gk[k * 384 + j];
    float o = gbias[j] + s;
    if (j < 256) o += gbias[384 + j];
    gbias2[j] = o;
  } else {
    gbias2[j] = gbias[256 + j];  // 640 + (j-384)
  }
}

__global__ __launch_bounds__(256) void repack_w(
    const float* __restrict__ w_next, const float* __restrict__ w_prev,
    unsigned short* __restrict__ pw2) {
  int idx = blockIdx.x * 256 + threadIdx.x;  // 0..32767
  int side = idx >> 14;
  int rr = idx & 16383;
  int c = rr >> 7, k = rr & 127;
  const float* src = side ? w_prev : w_next;
  float v = src[k * 128 + c];
  int nh = c >> 6, nb = (c >> 4) & 3, l15 = c & 15;
  int ks = k >> 5, lg = (k >> 3) & 3, j = k & 7;
  int lane = lg * 16 + l15;
  int e = nh * 16384 + ks * 4096 + nb * 1024 + side * 512 + lane * 8 + j;
  pw2[e] = (unsigned short)f2bf_u(v);
}

// ---------------------------------------------------------------- x -> bf16 (+fused edge histogram)
__global__ __launch_bounds__(256) void xbf_hist_kernel(
    const float* __restrict__ x, unsigned short* __restrict__ xbf,
    const int* __restrict__ pp, const int* __restrict__ pn,
    unsigned* __restrict__ cnt) {
  size_t i = ((size_t)blockIdx.x * 256 + threadIdx.x) * 8;
  if (i < (size_t)N_NODES * FDIM) {
    float4 a = *(const float4*)(x + i);
    float4 b = *(const float4*)(x + i + 4);
    uint4 o = make_uint4(f2bf2(a.x, a.y), f2bf2(a.z, a.w), f2bf2(b.x, b.y),
                         f2bf2(b.z, b.w));
    *(uint4*)(xbf + i) = o;
  }
  int e = blockIdx.x * 256 + threadIdx.x;
  if (e < 2 * E_EDGES) {
    int side = e >= E_EDGES;
    const int* pair = side ? pn + 2 * (e - E_EDGES) : pp + 2 * e;
    atomicAdd(&cnt[side * N_NODES + pair[0]], 1u);
  }
}

// ---------------------------------------------------------------- CSR build
__global__ __launch_bounds__(256) void scan1_kernel(const unsigned* __restrict__ cnt,
                                                    unsigned* __restrict__ off,
                                                    unsigned* __restrict__ part) {
  __shared__ unsigned ls[256];
  int side = blockIdx.y;
  int b = blockIdx.x;
  int td = threadIdx.x;
  int base = b * 1024 + td * 4;
  const unsigned* c = cnt + (size_t)side * N_NODES;
  unsigned v0 = 0, v1 = 0, v2 = 0, v3 = 0;
  if (base + 3 < N_NODES) {
    v0 = c[base]; v1 = c[base + 1]; v2 = c[base + 2]; v3 = c[base + 3];
  } else {
    if (base < N_NODES) v0 = c[base];
    if (base + 1 < N_NODES) v1 = c[base + 1];
    if (base + 2 < N_NODES) v2 = c[base + 2];
  }
  unsigned s = v0 + v1 + v2 + v3;
  ls[td] = s;
  __syncthreads();
  unsigned run = s;
  for (int st = 1; st < 256; st <<= 1) {
    unsigned o = (td >= st) ? ls[td - st] : 0u;
    __syncthreads();
    run += o;
    ls[td] = run;
    __syncthreads();
  }
  unsigned excl = run - s;
  unsigned* oo = off + (size_t)side * OFFS;
  if (base < N_NODES) oo[base] = excl;
  if (base + 1 < N_NODES) oo[base + 1] = excl + v0;
  if (base + 2 < N_NODES) oo[base + 2] = excl + v0 + v1;
  if (base + 3 < N_NODES) oo[base + 3] = excl + v0 + v1 + v2;
  if (td == 255) part[side * 512 + b] = run;
}

__global__ __launch_bounds__(1024) void scan2_kernel(unsigned* __restrict__ part) {
  __shared__ unsigned ls[1024];
  int td = threadIdx.x;
  int b = td & 511;
  unsigned s = part[td];
  ls[td] = s;
  __syncthreads();
  unsigned run = s;
  for (int st = 1; st < 512; st <<= 1) {
    unsigned o = (b >= st) ? ls[td - st] : 0u;
    __syncthreads();
    run += o;
    ls[td] = run;
    __syncthreads();
  }
  part[td] = run - s;
}

__global__ __launch_bounds__(256) void scan3_kernel(unsigned* __restrict__ off,
                                                    const unsigned* __restrict__ part,
                                                    unsigned* __restrict__ cur) {
  int side = blockIdx.y;
  int i = blockIdx.x * 256 + threadIdx.x;
  if (i < N_NODES) {
    unsigned v = off[(size_t)side * OFFS + i] + part[side * 512 + (i >> 10)];
    off[(size_t)side * OFFS + i] = v;
    cur[(size_t)side * N_NODES + i] = v;
  }
  if (i == 0) off[(size_t)side * OFFS + N_NODES] = E_EDGES;
}

__global__ __launch_bounds__(256) void reorder_kernel(const int* __restrict__ pp,
                                                      const int* __restrict__ pn,
                                                      unsigned* __restrict__ cur,
                                                      unsigned* __restrict__ srcbuf) {
  int i = blockIdx.x * 256 + threadIdx.x;
  if (i >= 2 * E_EDGES) return;
  int side = i >= E_EDGES;
  const int* pair = side ? pn + 2 * (i - E_EDGES) : pp + 2 * i;
  unsigned pos = atomicAdd(&cur[(size_t)side * N_NODES + pair[0]], 1u);
  srcbuf[(size_t)side * E_EDGES + pos] = (unsigned)pair[1];
}

// ---------------------------------------------------------------- fused gather + aggre MFMA + relu + BN-stats
// Gather: (1) cooperatively stage the block's contiguous src-index windows in
// LDS (breaks the srcbuf->xbf dependent chain), (2) per-side 2-deep software-
// pipelined edge loop (load j+1 while accumulating j). Per-side accumulation
// order unchanged -> numerics bit-identical.
__global__ __launch_bounds__(256) void aggre_fused(
    const unsigned short* __restrict__ xbf, const unsigned* __restrict__ off,
    const unsigned* __restrict__ srcbuf, const unsigned short* __restrict__ pw2,
    const float* __restrict__ b, unsigned short* __restrict__ a_out,
    float* __restrict__ buckets) {
  __shared__ unsigned short Ap[32 * 128];   // 8 KB
  __shared__ unsigned short An[32 * 128];   // 8 KB
  __shared__ unsigned soff[2][33];
  __shared__ unsigned ssrc[2][SCAP];        // 1.28 KB
  __shared__ float rs[2][128];
  __shared__ float rq[2][128];
  int t = threadIdx.x;
  int r0 = blockIdx.x * 32;
  int rr = t >> 3, fc = t & 7;  // gather role: my row, my 16-feature chunk

  if (t < 33) soff[0][t] = off[r0 + t];
  if (t >= 64 && t < 97) soff[1][t - 64] = off[(size_t)OFFS + r0 + (t - 64)];
  __syncthreads();

  unsigned e0p = soff[0][0], cP = soff[0][32] - e0p;
  unsigned e0n = soff[1][0], cN = soff[1][32] - e0n;
  const unsigned* slp = srcbuf;
  const unsigned* sln = srcbuf + E_EDGES;
  bool stP = cP <= (unsigned)SCAP, stN = cN <= (unsigned)SCAP;
  if (stP)
    for (unsigned i = t; i < cP; i += 256) ssrc[0][i] = slp[e0p + i];
  if (stN)
    for (unsigned i = t; i < cN; i += 256) ssrc[1][i] = sln[e0n + i];
  __syncthreads();

#pragma unroll
  for (int side = 0; side < 2; ++side) {
    unsigned s0 = soff[side][rr], s1 = soff[side][rr + 1];
    unsigned base = side ? e0n : e0p;
    bool st = side ? stN : stP;
    const unsigned* gl = side ? sln : slp;
    float a[16];
#pragma unroll
    for (int i = 0; i < 16; ++i) a[i] = 0.f;

    unsigned n = s1 - s0;
    uint4 c0, c1, n0, n1;
    if (n) {
      unsigned idx = st ? ssrc[side][s0 - base] : gl[s0];
      const unsigned short* p = xbf + (size_t)idx * FDIM + fc * 16;
      c0 = *(const uint4*)p;
      c1 = *(const uint4*)(p + 8);
    }
    for (unsigned j = 0; j < n; ++j) {
      if (j + 1 < n) {
        unsigned idx = st ? ssrc[side][s0 - base + j + 1] : gl[s0 + j + 1];
        const unsigned short* p = xbf + (size_t)idx * FDIM + fc * 16;
        n0 = *(const uint4*)p;
        n1 = *(const uint4*)(p + 8);
      }
      acc16(a, c0, c1);
      c0 = n0;
      c1 = n1;
    }

    unsigned short* dstl = side ? An : Ap;
    int b0 = (rr * 256 + fc * 32) ^ ((rr & 7) << 4);
    int b1 = (rr * 256 + fc * 32 + 16) ^ ((rr & 7) << 4);
    uint4 o0 = make_uint4(f2bf2(a[0], a[1]), f2bf2(a[2], a[3]),
                          f2bf2(a[4], a[5]), f2bf2(a[6], a[7]));
    uint4 o1 = make_uint4(f2bf2(a[8], a[9]), f2bf2(a[10], a[11]),
                          f2bf2(a[12], a[13]), f2bf2(a[14], a[15]));
    *(uint4*)((char*)dstl + b0) = o0;
    *(uint4*)((char*)dstl + b1) = o1;
  }
  __syncthreads();

  // ---- MFMA phase ----
  int w = t >> 6, lane = t & 63;
  int m0 = (w & 1) * 16, nh = w >> 1;
  int l15 = lane & 15, lg = lane >> 4;

  v4f acc[4];
#pragma unroll
  for (int nb = 0; nb < 4; ++nb) acc[nb] = (v4f){0.f, 0.f, 0.f, 0.f};

#pragma unroll
  for (int ks = 0; ks < 4; ++ks) {
    int mm = m0 + l15;
    int byte = (mm * 256 + ks * 64 + lg * 16) ^ ((mm & 7) << 4);
    v8bf apf = __builtin_bit_cast(v8bf, *(const uint4*)((const char*)Ap + byte));
    v8bf anf = __builtin_bit_cast(v8bf, *(const uint4*)((const char*)An + byte));
    const unsigned short* wb = pw2 + nh * 16384 + ks * 4096 + lane * 8;
#pragma unroll
    for (int nb = 0; nb < 4; ++nb) {
      v8bf bn_ = __builtin_bit_cast(v8bf, *(const uint4*)(wb + nb * 1024));
      v8bf bp_ = __builtin_bit_cast(v8bf, *(const uint4*)(wb + nb * 1024 + 512));
      acc[nb] = __builtin_amdgcn_mfma_f32_16x16x32_bf16(anf, bn_, acc[nb], 0, 0, 0);
      acc[nb] = __builtin_amdgcn_mfma_f32_16x16x32_bf16(apf, bp_, acc[nb], 0, 0, 0);
    }
  }

  float s1[4], s2[4];
#pragma unroll
  for (int nb = 0; nb < 4; ++nb) {
    int c = nh * 64 + nb * 16 + l15;
    float bb = b[c];
    s1[nb] = 0.f;
    s2[nb] = 0.f;
#pragma unroll
    for (int r = 0; r < 4; ++r) {
      int row = r0 + m0 + 4 * lg + r;
      size_t o = (size_t)row * FDIM + c;
      float v = acc[nb][r] + bb + bf2f(xbf[o]);
      v = fmaxf(v, 0.f);
      a_out[o] = (unsigned short)f2bf_u(v);
      s1[nb] += v;
      s2[nb] += v * v;
    }
    s1[nb] += __shfl_xor(s1[nb], 16);
    s1[nb] += __shfl_xor(s1[nb], 32);
    s2[nb] += __shfl_xor(s2[nb], 16);
    s2[nb] += __shfl_xor(s2[nb], 32);
  }
  if (lane < 16) {
#pragma unroll
    for (int nb = 0; nb < 4; ++nb) {
      rs[w & 1][nh * 64 + nb * 16 + lane] = s1[nb];
      rq[w & 1][nh * 64 + nb * 16 + lane] = s2[nb];
    }
  }
  __syncthreads();
  if (t < 128) {
    float s = rs[0][t] + rs[1][t];
    float q = rq[0][t] + rq[1][t];
    float* bkt = buckets + (size_t)(blockIdx.x & 63) * 256;
    atomicAdd(bkt + t, s);
    atomicAdd(bkt + 128 + t, q);
  }
}

// ---------------------------------------------------------------- BN finalize
__global__ void bn_finalize(const float* __restrict__ buckets,
                            const float* __restrict__ gamma,
                            const float* __restrict__ beta,
                            float* __restrict__ scaleshift) {
  int t = threadIdx.x;  // 128
  float s = 0.f, q = 0.f;
  for (int j = 0; j < 64; ++j) {
    s += buckets[j * 256 + t];
    q += buckets[j * 256 + 128 + t];
  }
  float mean = s / (float)N_NODES;
  float var = q / (float)N_NODES - mean * mean;
  var = fmaxf(var, 0.f);
  float sc = gamma[t] * rsqrtf(var + BN_EPS);
  scaleshift[t] = sc;
  scaleshift[128 + t] = beta[t] - mean * sc;
}

// ---------------------------------------------------------------- GRU v7 (MFMA)
__global__ __launch_bounds__(256) void gru_mfma(
    const unsigned short* __restrict__ a_bf, const unsigned short* __restrict__ xbf,
    const unsigned short* __restrict__ pw, const float* __restrict__ gbias2,
    float* __restrict__ out) {
  __shared__ unsigned short Aa[32 * 128];  // raw a bf16, swizzled
  __shared__ unsigned short Ax[32 * 128];  // x bf16, swizzled
  int t = threadIdx.x;
  int r0 = blockIdx.x * 32;

#pragma unroll
  for (int i = 0; i < 2; ++i) {
    int q = t + 256 * i;  // 0..511 : 32 rows x 16 chunks of 8 feats
    int row = q >> 4, kq = q & 15;
    size_t g = (size_t)(r0 + row) * FDIM + kq * 8;
    uint4 av = *(const uint4*)(a_bf + g);
    uint4 xv = *(const uint4*)(xbf + g);
    int byte = (row * 256 + kq * 16) ^ ((row & 7) << 4);
    *(uint4*)((char*)Aa + byte) = av;  // raw copies — zero conversion VALU
    *(uint4*)((char*)Ax + byte) = xv;
  }
  __syncthreads();

  int w = t >> 6, lane = t & 63;
  int l15 = lane & 15, lg = lane >> 4;

  v4f az[2][2], ar[2][2], ah0[2][2], ah1[2][2];  // [m][nb]
#pragma unroll
  for (int m = 0; m < 2; ++m)
#pragma unroll
    for (int nb = 0; nb < 2; ++nb) {
      az[m][nb] = (v4f){0.f, 0.f, 0.f, 0.f};
      ar[m][nb] = (v4f){0.f, 0.f, 0.f, 0.f};
      ah0[m][nb] = (v4f){0.f, 0.f, 0.f, 0.f};
      ah1[m][nb] = (v4f){0.f, 0.f, 0.f, 0.f};
    }

#pragma unroll
  for (int ks = 0; ks < 4; ++ks) {
    v8bf aa[2], ax[2];
#pragma unroll
    for (int m = 0; m < 2; ++m) {
      int mm = m * 16 + l15;
      int byte = (mm * 256 + ks * 64 + lg * 16) ^ ((mm & 7) << 4);
      aa[m] = __builtin_bit_cast(v8bf, *(const uint4*)((const char*)Aa + byte));
      ax[m] = __builtin_bit_cast(v8bf, *(const uint4*)((const char*)Ax + byte));
    }
    const unsigned short* wb = pw + w * 24576 + ks * 6144 + lane * 8;
#pragma unroll
    for (int nb = 0; nb < 2; ++nb) {
      const unsigned short* wn = wb + nb * 3072;
      v8bf b0z = __builtin_bit_cast(v8bf, *(const uint4*)(wn));
      v8bf b1z = __builtin_bit_cast(v8bf, *(const uint4*)(wn + 512));
      v8bf b0r = __builtin_bit_cast(v8bf, *(const uint4*)(wn + 1024));
      v8bf b1r = __builtin_bit_cast(v8bf, *(const uint4*)(wn + 1536));
      v8bf b0h = __builtin_bit_cast(v8bf, *(const uint4*)(wn + 2048));
      v8bf b1h = __builtin_bit_cast(v8bf, *(const uint4*)(wn + 2560));
#pragma unroll
      for (int m = 0; m < 2; ++m) {
        az[m][nb] = __builtin_amdgcn_mfma_f32_16x16x32_bf16(aa[m], b0z, az[m][nb], 0, 0, 0);
        az[m][nb] = __builtin_amdgcn_mfma_f32_16x16x32_bf16(ax[m], b1z, az[m][nb], 0, 0, 0);
        ar[m][nb] = __builtin_amdgcn_mfma_f32_16x16x32_bf16(aa[m], b0r, ar[m][nb], 0, 0, 0);
        ar[m][nb] = __builtin_amdgcn_mfma_f32_16x16x32_bf16(ax[m], b1r, ar[m][nb], 0, 0, 0);
        ah0[m][nb] = __builtin_amdgcn_mfma_f32_16x16x32_bf16(aa[m], b0h, ah0[m][nb], 0, 0, 0);
        ah1[m][nb] = __builtin_amdgcn_mfma_f32_16x16x32_bf16(ax[m], b1h, ah1[m][nb], 0, 0, 0);
      }
    }
  }

#pragma unroll
  for (int nb = 0; nb < 2; ++nb) {
    int c = w * 32 + nb * 16 + l15;
    float bz = gbias2[c];
    float br = gbias2[128 + c];
    float bh0 = gbias2[256 + c];
    float bh1 = gbias2[384 + c];
#pragma unroll
    for (int m = 0; m < 2; ++m) {
#pragma unroll
      for (int r = 0; r < 4; ++r) {
        int rl = m * 16 + 4 * lg + r;
        int row = r0 + rl;
        float z = fast_sigmoid(az[m][nb][r] + bz);
        float rg = fast_sigmoid(ar[m][nb][r] + br);
        float hc = fast_tanh(ah0[m][nb][r] + bh0 + rg * (ah1[m][nb][r] + bh1));
        int hb = (rl * 256 + c * 2) ^ ((rl & 7) << 4);
        float h = bf2f(*(const unsigned short*)((const char*)Ax + hb));
        __builtin_nontemporal_store(hc + z * (h - hc),
                                    out + (size_t)row * FDIM + c);
      }
    }
  }
}

// ---------------------------------------------------------------- launch
extern "C" void kernel_launch(void* const* d_in, const int* in_sizes, int n_in,
                              void* d_out, int out_size, void* d_ws, size_t ws_size,
                              hipStream_t stream) {
  const float* x = (const float*)d_in[0];
  const int* pp = (const int*)d_in[1];
  const int* pn = (const int*)d_in[2];
  const float* w_next = (const float*)d_in[3];
  const float* w_prev = (const float*)d_in[4];
  const float* b = (const float*)d_in[5];
  const float* gamma = (const float*)d_in[6];
  const float* beta = (const float*)d_in[7];
  const float* gk = (const float*)d_in[8];
  const float* rk = (const float*)d_in[9];
  const float* gbias = (const float*)d_in[10];
  float* out = (float*)d_out;
  float* ws = (float*)d_ws;

  float* buckets = ws + WS_BUCKETS;
  float* gbias2 = ws + WS_BUCKETS;  // reuses buckets after bn_finalize
  float* scaleshift = ws + WS_SCALESHIFT;
  unsigned short* pw = (unsigned short*)(ws + WS_PW);
  unsigned short* pw2 = (unsigned short*)(ws + WS_PW2);
  unsigned short* xbf = (unsigned short*)(ws + WS_XBF);
  unsigned short* a_bf = xbf + (size_t)N_NODES * FDIM;  // 128 MB after xbf

  unsigned* u = (unsigned*)d_out;  // CSR scratch; dead before gru writes out
  unsigned* cnt = u + SO_CNT;
  unsigned* off = u + SO_OFF;
  unsigned* part = u + SO_PART;
  unsigned* cur = u + SO_CUR;
  unsigned* srcbuf = u + SO_SRC;

  hipMemsetAsync(cnt, 0, 2u * N_NODES * sizeof(unsigned), stream);
  hipMemsetAsync(part, 0, 1024 * sizeof(unsigned), stream);
  hipMemsetAsync(buckets, 0, (16384 + 256) * sizeof(float), stream);

  repack_w<<<128, 256, 0, stream>>>(w_next, w_prev, pw2);
  xbf_hist_kernel<<<31250, 256, 0, stream>>>(x, xbf, pp, pn, cnt);

  scan1_kernel<<<dim3(489, 2), 256, 0, stream>>>(cnt, off, part);
  scan2_kernel<<<1, 1024, 0, stream>>>(part);
  scan3_kernel<<<dim3((N_NODES + 255) / 256, 2), 256, 0, stream>>>(off, part, cur);
  reorder_kernel<<<(2 * E_EDGES + 255) / 256, 256, 0, stream>>>(pp, pn, cur, srcbuf);

  aggre_fused<<<N_NODES / 32, 256, 0, stream>>>(xbf, off, srcbuf, pw2, b, a_bf,
                                                buckets);
  bn_finalize<<<1, 128, 0, stream>>>(buckets, gamma, beta, scaleshift);
  // post-BN: fold scale into a-side GRU weights, shift@W into biases
  repack_gru_scaled<<<384, 256, 0, stream>>>(gk, rk, scaleshift, pw);
  bias_fold<<<1, 512, 0, stream>>>(gk, gbias, scaleshift, gbias2);
  gru_mfma<<<N_NODES / 32, 256, 0, stream>>>(a_bf, xbf, pw, gbias2, out);
}

// Round 15
// 503.906 us; speedup vs baseline: 1.0289x; 1.0119x over previous
//
#include <hip/hip_runtime.h>
#include <hip/hip_bf16.h>

#define N_NODES 500000
#define E_EDGES 500000
#define FDIM 128
#define BN_EPS 1e-3f
#define OFFS 500001  // per-side stride of the offsets array
#define SCAP 160     // staged src indices per side per block (fallback if exceeded)

// ws layout (in floats):
//   [0, 16384)        buckets: 64 x (sum[128], sumsq[128]); after bn_finalize the
//                     first 512 floats are reused as gbias2 (folded GRU biases)
//   [16384, 16640)    scaleshift: scale[128], shift[128]
//   [16640, 65792)    pw  (gru weights)  bf16 fragment-order, 192 KB
//                     side 0 (a-side) is SCALED by BN scale post-bn_finalize
//   [65792, 82176)    pw2 (aggre weights) bf16 fragment-order, 64 KB
//   [82176, +32e6)    xbf  [N][128] bf16 (128 MB)
//   [.., +32e6)       a_bf [N][128] bf16 (128 MB)
#define WS_BUCKETS 0
#define WS_SCALESHIFT 16384
#define WS_PW 16640
#define WS_PW2 65792
#define WS_XBF 82176

// d_out u32 scratch layout (CSR only; dead before gru writes d_out):
#define SO_CNT 0
#define SO_OFF 1000000
#define SO_PART 2100000
#define SO_CUR 2200000
#define SO_SRC 3200000   // ends at 16.8 MB

typedef __attribute__((ext_vector_type(4))) float v4f;
typedef __attribute__((ext_vector_type(8))) __bf16 v8bf;

__device__ __forceinline__ unsigned f2bf_u(float f) {
  unsigned u = __float_as_uint(f);
  return ((u + 0x7FFF + ((u >> 16) & 1)) >> 16) & 0xFFFF;
}
__device__ __forceinline__ unsigned f2bf2(float a, float b) {
  return f2bf_u(a) | (f2bf_u(b) << 16);
}
__device__ __forceinline__ float bf2f(unsigned short u) {
  return __uint_as_float((unsigned)u << 16);
}
__device__ __forceinline__ float fast_sigmoid(float x) {
  float e = __expf(-x);
  return __builtin_amdgcn_rcpf(1.f + e);
}
// tanh(y) = 2*sigmoid(2y) - 1 ; saturates correctly at +/-inf without clamps.
__device__ __forceinline__ float fast_tanh(float x) {
  float e = __expf(-2.f * x);
  return 2.f * __builtin_amdgcn_rcpf(1.f + e) - 1.f;
}

__device__ __forceinline__ void acc16(float* a, uint4 u0, uint4 u1) {
  a[0] += bf2f((unsigned short)(u0.x & 0xffff)); a[1] += __uint_as_float(u0.x & 0xffff0000u);
  a[2] += bf2f((unsigned short)(u0.y & 0xffff)); a[3] += __uint_as_float(u0.y & 0xffff0000u);
  a[4] += bf2f((unsigned short)(u0.z & 0xffff)); a[5] += __uint_as_float(u0.z & 0xffff0000u);
  a[6] += bf2f((unsigned short)(u0.w & 0xffff)); a[7] += __uint_as_float(u0.w & 0xffff0000u);
  a[8] += bf2f((unsigned short)(u1.x & 0xffff)); a[9] += __uint_as_float(u1.x & 0xffff0000u);
  a[10] += bf2f((unsigned short)(u1.y & 0xffff)); a[11] += __uint_as_float(u1.y & 0xffff0000u);
  a[12] += bf2f((unsigned short)(u1.z & 0xffff)); a[13] += __uint_as_float(u1.z & 0xffff0000u);
  a[14] += bf2f((unsigned short)(u1.w & 0xffff)); a[15] += __uint_as_float(u1.w & 0xffff0000u);
}

// ---------------------------------------------------------------- weight repack
__global__ __launch_bounds__(256) void repack_gru_scaled(
    const float* __restrict__ gk, const float* __restrict__ rk,
    const float* __restrict__ scaleshift, unsigned short* __restrict__ pw) {
  int idx = blockIdx.x * 256 + threadIdx.x;  // 0..98303
  int side = idx / 49152;
  int rem = idx % 49152;
  int gate = rem >> 14;
  int rr = rem & 16383;
  int c = rr >> 7, k = rr & 127;
  const float* src = side ? rk : gk;
  float v = src[k * 384 + gate * 128 + c];
  if (side == 0) v *= scaleshift[k];
  int w = c >> 5, nb = (c >> 4) & 1, l15 = c & 15;
  int ks = k >> 5, lg = (k >> 3) & 3, j = k & 7;
  int lane = lg * 16 + l15;
  int e = w * 24576 + ks * 6144 + nb * 3072 + gate * 1024 + side * 512 + lane * 8 + j;
  pw[e] = (unsigned short)f2bf_u(v);
}

// Folded GRU bias (incl. shift @ gk).
__global__ __launch_bounds__(512) void bias_fold(
    const float* __restrict__ gk, const float* __restrict__ gbias,
    const float* __restrict__ scaleshift, float* __restrict__ gbias2) {
  __shared__ float sh[128];
  int j = threadIdx.x;
  if (j < 128) sh[j] = scaleshift[128 + j];
  __syncthreads();
  if (j < 384) {
    float s = 0.f;
#pragma unroll 8
    for (int k = 0; k < 128; ++k) s += sh[k] * gk[k * 384 + j];
    float o = gbias[j] + s;
    if (j < 256) o += gbias[384 + j];
    gbias2[j] = o;
  } else {
    gbias2[j] = gbias[256 + j];  // 640 + (j-384)
  }
}

__global__ __launch_bounds__(256) void repack_w(
    const float* __restrict__ w_next, const float* __restrict__ w_prev,
    unsigned short* __restrict__ pw2) {
  int idx = blockIdx.x * 256 + threadIdx.x;  // 0..32767
  int side = idx >> 14;
  int rr = idx & 16383;
  int c = rr >> 7, k = rr & 127;
  const float* src = side ? w_prev : w_next;
  float v = src[k * 128 + c];
  int nh = c >> 6, nb = (c >> 4) & 3, l15 = c & 15;
  int ks = k >> 5, lg = (k >> 3) & 3, j = k & 7;
  int lane = lg * 16 + l15;
  int e = nh * 16384 + ks * 4096 + nb * 1024 + side * 512 + lane * 8 + j;
  pw2[e] = (unsigned short)f2bf_u(v);
}

// ---------------------------------------------------------------- x -> bf16 (+fused edge histogram)
__global__ __launch_bounds__(256) void xbf_hist_kernel(
    const float* __restrict__ x, unsigned short* __restrict__ xbf,
    const int* __restrict__ pp, const int* __restrict__ pn,
    unsigned* __restrict__ cnt) {
  size_t i = ((size_t)blockIdx.x * 256 + threadIdx.x) * 8;
  if (i < (size_t)N_NODES * FDIM) {
    float4 a = *(const float4*)(x + i);
    float4 b = *(const float4*)(x + i + 4);
    uint4 o = make_uint4(f2bf2(a.x, a.y), f2bf2(a.z, a.w), f2bf2(b.x, b.y),
                         f2bf2(b.z, b.w));
    *(uint4*)(xbf + i) = o;
  }
  int e = blockIdx.x * 256 + threadIdx.x;
  if (e < 2 * E_EDGES) {
    int side = e >= E_EDGES;
    const int* pair = side ? pn + 2 * (e - E_EDGES) : pp + 2 * e;
    atomicAdd(&cnt[side * N_NODES + pair[0]], 1u);
  }
}

// ---------------------------------------------------------------- CSR build
__global__ __launch_bounds__(256) void scan1_kernel(const unsigned* __restrict__ cnt,
                                                    unsigned* __restrict__ off,
                                                    unsigned* __restrict__ part) {
  __shared__ unsigned ls[256];
  int side = blockIdx.y;
  int b = blockIdx.x;
  int td = threadIdx.x;
  int base = b * 1024 + td * 4;
  const unsigned* c = cnt + (size_t)side * N_NODES;
  unsigned v0 = 0, v1 = 0, v2 = 0, v3 = 0;
  if (base + 3 < N_NODES) {
    v0 = c[base]; v1 = c[base + 1]; v2 = c[base + 2]; v3 = c[base + 3];
  } else {
    if (base < N_NODES) v0 = c[base];
    if (base + 1 < N_NODES) v1 = c[base + 1];
    if (base + 2 < N_NODES) v2 = c[base + 2];
  }
  unsigned s = v0 + v1 + v2 + v3;
  ls[td] = s;
  __syncthreads();
  unsigned run = s;
  for (int st = 1; st < 256; st <<= 1) {
    unsigned o = (td >= st) ? ls[td - st] : 0u;
    __syncthreads();
    run += o;
    ls[td] = run;
    __syncthreads();
  }
  unsigned excl = run - s;
  unsigned* oo = off + (size_t)side * OFFS;
  if (base < N_NODES) oo[base] = excl;
  if (base + 1 < N_NODES) oo[base + 1] = excl + v0;
  if (base + 2 < N_NODES) oo[base + 2] = excl + v0 + v1;
  if (base + 3 < N_NODES) oo[base + 3] = excl + v0 + v1 + v2;
  if (td == 255) part[side * 512 + b] = run;
}

__global__ __launch_bounds__(1024) void scan2_kernel(unsigned* __restrict__ part) {
  __shared__ unsigned ls[1024];
  int td = threadIdx.x;
  int b = td & 511;
  unsigned s = part[td];
  ls[td] = s;
  __syncthreads();
  unsigned run = s;
  for (int st = 1; st < 512; st <<= 1) {
    unsigned o = (b >= st) ? ls[td - st] : 0u;
    __syncthreads();
    run += o;
    ls[td] = run;
    __syncthreads();
  }
  part[td] = run - s;
}

__global__ __launch_bounds__(256) void scan3_kernel(unsigned* __restrict__ off,
                                                    const unsigned* __restrict__ part,
                                                    unsigned* __restrict__ cur) {
  int side = blockIdx.y;
  int i = blockIdx.x * 256 + threadIdx.x;
  if (i < N_NODES) {
    unsigned v = off[(size_t)side * OFFS + i] + part[side * 512 + (i >> 10)];
    off[(size_t)side * OFFS + i] = v;
    cur[(size_t)side * N_NODES + i] = v;
  }
  if (i == 0) off[(size_t)side * OFFS + N_NODES] = E_EDGES;
}

__global__ __launch_bounds__(256) void reorder_kernel(const int* __restrict__ pp,
                                                      const int* __restrict__ pn,
                                                      unsigned* __restrict__ cur,
                                                      unsigned* __restrict__ srcbuf) {
  int i = blockIdx.x * 256 + threadIdx.x;
  if (i >= 2 * E_EDGES) return;
  int side = i >= E_EDGES;
  const int* pair = side ? pn + 2 * (i - E_EDGES) : pp + 2 * i;
  unsigned pos = atomicAdd(&cur[(size_t)side * N_NODES + pair[0]], 1u);
  srcbuf[(size_t)side * E_EDGES + pos] = (unsigned)pair[1];
}

// ---------------------------------------------------------------- fused gather + aggre MFMA + relu + BN-stats
// (unchanged from round 14)
__global__ __launch_bounds__(256) void aggre_fused(
    const unsigned short* __restrict__ xbf, const unsigned* __restrict__ off,
    const unsigned* __restrict__ srcbuf, const unsigned short* __restrict__ pw2,
    const float* __restrict__ b, unsigned short* __restrict__ a_out,
    float* __restrict__ buckets) {
  __shared__ unsigned short Ap[32 * 128];   // 8 KB
  __shared__ unsigned short An[32 * 128];   // 8 KB
  __shared__ unsigned soff[2][33];
  __shared__ unsigned ssrc[2][SCAP];        // 1.28 KB
  __shared__ float rs[2][128];
  __shared__ float rq[2][128];
  int t = threadIdx.x;
  int r0 = blockIdx.x * 32;
  int rr = t >> 3, fc = t & 7;  // gather role: my row, my 16-feature chunk

  if (t < 33) soff[0][t] = off[r0 + t];
  if (t >= 64 && t < 97) soff[1][t - 64] = off[(size_t)OFFS + r0 + (t - 64)];
  __syncthreads();

  unsigned e0p = soff[0][0], cP = soff[0][32] - e0p;
  unsigned e0n = soff[1][0], cN = soff[1][32] - e0n;
  const unsigned* slp = srcbuf;
  const unsigned* sln = srcbuf + E_EDGES;
  bool stP = cP <= (unsigned)SCAP, stN = cN <= (unsigned)SCAP;
  if (stP)
    for (unsigned i = t; i < cP; i += 256) ssrc[0][i] = slp[e0p + i];
  if (stN)
    for (unsigned i = t; i < cN; i += 256) ssrc[1][i] = sln[e0n + i];
  __syncthreads();

#pragma unroll
  for (int side = 0; side < 2; ++side) {
    unsigned s0 = soff[side][rr], s1 = soff[side][rr + 1];
    unsigned base = side ? e0n : e0p;
    bool st = side ? stN : stP;
    const unsigned* gl = side ? sln : slp;
    float a[16];
#pragma unroll
    for (int i = 0; i < 16; ++i) a[i] = 0.f;

    unsigned n = s1 - s0;
    uint4 c0, c1, n0, n1;
    if (n) {
      unsigned idx = st ? ssrc[side][s0 - base] : gl[s0];
      const unsigned short* p = xbf + (size_t)idx * FDIM + fc * 16;
      c0 = *(const uint4*)p;
      c1 = *(const uint4*)(p + 8);
    }
    for (unsigned j = 0; j < n; ++j) {
      if (j + 1 < n) {
        unsigned idx = st ? ssrc[side][s0 - base + j + 1] : gl[s0 + j + 1];
        const unsigned short* p = xbf + (size_t)idx * FDIM + fc * 16;
        n0 = *(const uint4*)p;
        n1 = *(const uint4*)(p + 8);
      }
      acc16(a, c0, c1);
      c0 = n0;
      c1 = n1;
    }

    unsigned short* dstl = side ? An : Ap;
    int b0 = (rr * 256 + fc * 32) ^ ((rr & 7) << 4);
    int b1 = (rr * 256 + fc * 32 + 16) ^ ((rr & 7) << 4);
    uint4 o0 = make_uint4(f2bf2(a[0], a[1]), f2bf2(a[2], a[3]),
                          f2bf2(a[4], a[5]), f2bf2(a[6], a[7]));
    uint4 o1 = make_uint4(f2bf2(a[8], a[9]), f2bf2(a[10], a[11]),
                          f2bf2(a[12], a[13]), f2bf2(a[14], a[15]));
    *(uint4*)((char*)dstl + b0) = o0;
    *(uint4*)((char*)dstl + b1) = o1;
  }
  __syncthreads();

  // ---- MFMA phase ----
  int w = t >> 6, lane = t & 63;
  int m0 = (w & 1) * 16, nh = w >> 1;
  int l15 = lane & 15, lg = lane >> 4;

  v4f acc[4];
#pragma unroll
  for (int nb = 0; nb < 4; ++nb) acc[nb] = (v4f){0.f, 0.f, 0.f, 0.f};

#pragma unroll
  for (int ks = 0; ks < 4; ++ks) {
    int mm = m0 + l15;
    int byte = (mm * 256 + ks * 64 + lg * 16) ^ ((mm & 7) << 4);
    v8bf apf = __builtin_bit_cast(v8bf, *(const uint4*)((const char*)Ap + byte));
    v8bf anf = __builtin_bit_cast(v8bf, *(const uint4*)((const char*)An + byte));
    const unsigned short* wb = pw2 + nh * 16384 + ks * 4096 + lane * 8;
#pragma unroll
    for (int nb = 0; nb < 4; ++nb) {
      v8bf bn_ = __builtin_bit_cast(v8bf, *(const uint4*)(wb + nb * 1024));
      v8bf bp_ = __builtin_bit_cast(v8bf, *(const uint4*)(wb + nb * 1024 + 512));
      acc[nb] = __builtin_amdgcn_mfma_f32_16x16x32_bf16(anf, bn_, acc[nb], 0, 0, 0);
      acc[nb] = __builtin_amdgcn_mfma_f32_16x16x32_bf16(apf, bp_, acc[nb], 0, 0, 0);
    }
  }

  float s1[4], s2[4];
#pragma unroll
  for (int nb = 0; nb < 4; ++nb) {
    int c = nh * 64 + nb * 16 + l15;
    float bb = b[c];
    s1[nb] = 0.f;
    s2[nb] = 0.f;
#pragma unroll
    for (int r = 0; r < 4; ++r) {
      int row = r0 + m0 + 4 * lg + r;
      size_t o = (size_t)row * FDIM + c;
      float v = acc[nb][r] + bb + bf2f(xbf[o]);
      v = fmaxf(v, 0.f);
      a_out[o] = (unsigned short)f2bf_u(v);
      s1[nb] += v;
      s2[nb] += v * v;
    }
    s1[nb] += __shfl_xor(s1[nb], 16);
    s1[nb] += __shfl_xor(s1[nb], 32);
    s2[nb] += __shfl_xor(s2[nb], 16);
    s2[nb] += __shfl_xor(s2[nb], 32);
  }
  if (lane < 16) {
#pragma unroll
    for (int nb = 0; nb < 4; ++nb) {
      rs[w & 1][nh * 64 + nb * 16 + lane] = s1[nb];
      rq[w & 1][nh * 64 + nb * 16 + lane] = s2[nb];
    }
  }
  __syncthreads();
  if (t < 128) {
    float s = rs[0][t] + rs[1][t];
    float q = rq[0][t] + rq[1][t];
    float* bkt = buckets + (size_t)(blockIdx.x & 63) * 256;
    atomicAdd(bkt + t, s);
    atomicAdd(bkt + 128 + t, q);
  }
}

// ---------------------------------------------------------------- BN finalize
__global__ void bn_finalize(const float* __restrict__ buckets,
                            const float* __restrict__ gamma,
                            const float* __restrict__ beta,
                            float* __restrict__ scaleshift) {
  int t = threadIdx.x;  // 128
  float s = 0.f, q = 0.f;
  for (int j = 0; j < 64; ++j) {
    s += buckets[j * 256 + t];
    q += buckets[j * 256 + 128 + t];
  }
  float mean = s / (float)N_NODES;
  float var = q / (float)N_NODES - mean * mean;
  var = fmaxf(var, 0.f);
  float sc = gamma[t] * rsqrtf(var + BN_EPS);
  scaleshift[t] = sc;
  scaleshift[128 + t] = beta[t] - mean * sc;
}

// ---------------------------------------------------------------- GRU v8 (MFMA)
// 64 rows/block, 8 waves (512 thr). Wave w: rows (w>>2)*32..+31, cols (w&3)*32..+31.
// Wave pairs (rh=0/1, same cq) stream the SAME 48 KB weight slice on the same CU
// at the same barrier rhythm -> second read L1-hits, halving effective L2 traffic.
// Per-wave resources identical to the 32-row kernel (16 v4f accs).
__global__ __launch_bounds__(512) void gru_mfma(
    const unsigned short* __restrict__ a_bf, const unsigned short* __restrict__ xbf,
    const unsigned short* __restrict__ pw, const float* __restrict__ gbias2,
    float* __restrict__ out) {
  __shared__ unsigned short Aa[64 * 128];  // 16 KB raw a bf16, swizzled
  __shared__ unsigned short Ax[64 * 128];  // 16 KB x bf16, swizzled
  int t = threadIdx.x;
  int r0 = blockIdx.x * 64;

#pragma unroll
  for (int i = 0; i < 2; ++i) {
    int q = t + 512 * i;  // 0..1023 : 64 rows x 16 chunks of 8 feats
    int row = q >> 4, kq = q & 15;
    int gr = r0 + row;
    uint4 av = make_uint4(0, 0, 0, 0), xv = make_uint4(0, 0, 0, 0);
    if (gr < N_NODES) {
      size_t g = (size_t)gr * FDIM + kq * 8;
      av = *(const uint4*)(a_bf + g);
      xv = *(const uint4*)(xbf + g);
    }
    int byte = (row * 256 + kq * 16) ^ ((row & 7) << 4);
    *(uint4*)((char*)Aa + byte) = av;  // raw copies — zero conversion VALU
    *(uint4*)((char*)Ax + byte) = xv;
  }
  __syncthreads();

  int w = t >> 6, lane = t & 63;
  int rh = w >> 2, cq = w & 3;  // row-half, col-quarter
  int l15 = lane & 15, lg = lane >> 4;
  int rbase = rh * 32;

  v4f az[2][2], ar[2][2], ah0[2][2], ah1[2][2];  // [m][nb]
#pragma unroll
  for (int m = 0; m < 2; ++m)
#pragma unroll
    for (int nb = 0; nb < 2; ++nb) {
      az[m][nb] = (v4f){0.f, 0.f, 0.f, 0.f};
      ar[m][nb] = (v4f){0.f, 0.f, 0.f, 0.f};
      ah0[m][nb] = (v4f){0.f, 0.f, 0.f, 0.f};
      ah1[m][nb] = (v4f){0.f, 0.f, 0.f, 0.f};
    }

#pragma unroll
  for (int ks = 0; ks < 4; ++ks) {
    v8bf aa[2], ax[2];
#pragma unroll
    for (int m = 0; m < 2; ++m) {
      int mm = rbase + m * 16 + l15;
      int byte = (mm * 256 + ks * 64 + lg * 16) ^ ((mm & 7) << 4);
      aa[m] = __builtin_bit_cast(v8bf, *(const uint4*)((const char*)Aa + byte));
      ax[m] = __builtin_bit_cast(v8bf, *(const uint4*)((const char*)Ax + byte));
    }
    const unsigned short* wb = pw + cq * 24576 + ks * 6144 + lane * 8;
#pragma unroll
    for (int nb = 0; nb < 2; ++nb) {
      const unsigned short* wn = wb + nb * 3072;
      v8bf b0z = __builtin_bit_cast(v8bf, *(const uint4*)(wn));
      v8bf b1z = __builtin_bit_cast(v8bf, *(const uint4*)(wn + 512));
      v8bf b0r = __builtin_bit_cast(v8bf, *(const uint4*)(wn + 1024));
      v8bf b1r = __builtin_bit_cast(v8bf, *(const uint4*)(wn + 1536));
      v8bf b0h = __builtin_bit_cast(v8bf, *(const uint4*)(wn + 2048));
      v8bf b1h = __builtin_bit_cast(v8bf, *(const uint4*)(wn + 2560));
#pragma unroll
      for (int m = 0; m < 2; ++m) {
        az[m][nb] = __builtin_amdgcn_mfma_f32_16x16x32_bf16(aa[m], b0z, az[m][nb], 0, 0, 0);
        az[m][nb] = __builtin_amdgcn_mfma_f32_16x16x32_bf16(ax[m], b1z, az[m][nb], 0, 0, 0);
        ar[m][nb] = __builtin_amdgcn_mfma_f32_16x16x32_bf16(aa[m], b0r, ar[m][nb], 0, 0, 0);
        ar[m][nb] = __builtin_amdgcn_mfma_f32_16x16x32_bf16(ax[m], b1r, ar[m][nb], 0, 0, 0);
        ah0[m][nb] = __builtin_amdgcn_mfma_f32_16x16x32_bf16(aa[m], b0h, ah0[m][nb], 0, 0, 0);
        ah1[m][nb] = __builtin_amdgcn_mfma_f32_16x16x32_bf16(ax[m], b1h, ah1[m][nb], 0, 0, 0);
      }
    }
  }

#pragma unroll
  for (int nb = 0; nb < 2; ++nb) {
    int c = cq * 32 + nb * 16 + l15;
    float bz = gbias2[c];
    float br = gbias2[128 + c];
    float bh0 = gbias2[256 + c];
    float bh1 = gbias2[384 + c];
#pragma unroll
    for (int m = 0; m < 2; ++m) {
#pragma unroll
      for (int r = 0; r < 4; ++r) {
        int rl = rbase + m * 16 + 4 * lg + r;
        int row = r0 + rl;
        if (row < N_NODES) {
          float z = fast_sigmoid(az[m][nb][r] + bz);
          float rg = fast_sigmoid(ar[m][nb][r] + br);
          float hc = fast_tanh(ah0[m][nb][r] + bh0 + rg * (ah1[m][nb][r] + bh1));
          int hb = (rl * 256 + c * 2) ^ ((rl & 7) << 4);
          float h = bf2f(*(const unsigned short*)((const char*)Ax + hb));
          __builtin_nontemporal_store(hc + z * (h - hc),
                                      out + (size_t)row * FDIM + c);
        }
      }
    }
  }
}

// ---------------------------------------------------------------- launch
extern "C" void kernel_launch(void* const* d_in, const int* in_sizes, int n_in,
                              void* d_out, int out_size, void* d_ws, size_t ws_size,
                              hipStream_t stream) {
  const float* x = (const float*)d_in[0];
  const int* pp = (const int*)d_in[1];
  const int* pn = (const int*)d_in[2];
  const float* w_next = (const float*)d_in[3];
  const float* w_prev = (const float*)d_in[4];
  const float* b = (const float*)d_in[5];
  const float* gamma = (const float*)d_in[6];
  const float* beta = (const float*)d_in[7];
  const float* gk = (const float*)d_in[8];
  const float* rk = (const float*)d_in[9];
  const float* gbias = (const float*)d_in[10];
  float* out = (float*)d_out;
  float* ws = (float*)d_ws;

  float* buckets = ws + WS_BUCKETS;
  float* gbias2 = ws + WS_BUCKETS;  // reuses buckets after bn_finalize
  float* scaleshift = ws + WS_SCALESHIFT;
  unsigned short* pw = (unsigned short*)(ws + WS_PW);
  unsigned short* pw2 = (unsigned short*)(ws + WS_PW2);
  unsigned short* xbf = (unsigned short*)(ws + WS_XBF);
  unsigned short* a_bf = xbf + (size_t)N_NODES * FDIM;  // 128 MB after xbf

  unsigned* u = (unsigned*)d_out;  // CSR scratch; dead before gru writes out
  unsigned* cnt = u + SO_CNT;
  unsigned* off = u + SO_OFF;
  unsigned* part = u + SO_PART;
  unsigned* cur = u + SO_CUR;
  unsigned* srcbuf = u + SO_SRC;

  hipMemsetAsync(cnt, 0, 2u * N_NODES * sizeof(unsigned), stream);
  hipMemsetAsync(part, 0, 1024 * sizeof(unsigned), stream);
  hipMemsetAsync(buckets, 0, (16384 + 256) * sizeof(float), stream);

  repack_w<<<128, 256, 0, stream>>>(w_next, w_prev, pw2);
  xbf_hist_kernel<<<31250, 256, 0, stream>>>(x, xbf, pp, pn, cnt);

  scan1_kernel<<<dim3(489, 2), 256, 0, stream>>>(cnt, off, part);
  scan2_kernel<<<1, 1024, 0, stream>>>(part);
  scan3_kernel<<<dim3((N_NODES + 255) / 256, 2), 256, 0, stream>>>(off, part, cur);
  reorder_kernel<<<(2 * E_EDGES + 255) / 256, 256, 0, stream>>>(pp, pn, cur, srcbuf);

  aggre_fused<<<N_NODES / 32, 256, 0, stream>>>(xbf, off, srcbuf, pw2, b, a_bf,
                                                buckets);
  bn_finalize<<<1, 128, 0, stream>>>(buckets, gamma, beta, scaleshift);
  // post-BN: fold scale into a-side GRU weights, shift@W into biases
  repack_gru_scaled<<<384, 256, 0, stream>>>(gk, rk, scaleshift, pw);
  bias_fold<<<1, 512, 0, stream>>>(gk, gbias, scaleshift, gbias2);
  gru_mfma<<<(N_NODES + 63) / 64, 512, 0, stream>>>(a_bf, xbf, pw, gbias2, out);
}